// Round 13
// baseline (711.787 us; speedup 1.0000x reference)
//
#include <hip/hip_runtime.h>
#include <math.h>

#define T_FR   16
#define N_Q    128
#define NSUP   49
#define H0     96
#define W0     128
#define DIN    1110
#define ITERS  4
#define KCV    2560   // cv K: q*52+p, q<49, p<52 (p>=49 exact zeros), tail 2548..2559 zero
#define KU     1152   // padded 1110 (multiple of 64)

typedef __attribute__((ext_vector_type(8))) short short8;
typedef __attribute__((ext_vector_type(4))) float f32x4;

__device__ __forceinline__ float geluf(float x) {
    return 0.5f * x * (1.0f + erff(x * 0.70710678118654752f));
}
__device__ __forceinline__ unsigned short f2bf(float f) {
    unsigned u = __float_as_uint(f);
    u += 0x7fff + ((u >> 16) & 1);
    return (unsigned short)(u >> 16);
}
__device__ __forceinline__ float bf2f(unsigned short s) {
    return __uint_as_float(((unsigned)s) << 16);
}
__device__ __forceinline__ void async16(const void* g, void* l) {
    __builtin_amdgcn_global_load_lds(
        (const __attribute__((address_space(1))) void*)g,
        (__attribute__((address_space(3))) void*)l, 16, 0, 0);
}

// ---------------- time embedding interpolation (50 -> 16) ----------------
__global__ void k_te(const float* __restrict__ emb, float* __restrict__ te) {
    int i = blockIdx.x * 256 + threadIdx.x;
    if (i >= T_FR * DIN) return;
    int t = i / DIN, d = i - t * DIN;
    float j = ((float)t + 0.5f) * (50.0f / 16.0f) - 0.5f;
    j = fminf(fmaxf(j, 0.0f), 49.0f);
    float j0f = floorf(j);
    int j0 = (int)j0f;
    int j1 = min(j0 + 1, 49);
    float w = j - j0f;
    te[i] = emb[j0 * DIN + d] * (1.0f - w) + emb[j1 * DIN + d] * w;
}

// ---------------- state init ----------------
__global__ void k_init(const float* __restrict__ q, float* __restrict__ coords,
                       float* __restrict__ vis, float* __restrict__ conf) {
    int r = blockIdx.x * 256 + threadIdx.x;
    if (r >= T_FR * N_Q) return;
    int n = r & 127;
    coords[r * 2 + 0] = q[n * 3 + 1] * 0.25f;
    coords[r * 2 + 1] = q[n * 3 + 2] * 0.25f;
    vis[r] = 0.0f;
    conf[r] = 0.0f;
}

// ---------------- fc1 weight prep: (2401,384) fp32 -> bf16 (384, KCV) permuted ----------------
__global__ void k_prep1(const float* __restrict__ w, unsigned short* __restrict__ wt) {
    int i = blockIdx.x * 256 + threadIdx.x;
    if (i >= 2401 * 384) return;
    int k = i / 384, n = i - k * 384;
    int p = k / 49, q = k - p * 49;
    wt[(size_t)n * KCV + q * 52 + p] = f2bf(w[i]);
}

// ---------------- generic weight prep: fp32 (K,N) -> bf16 transposed (N,Ka) ----------------
__global__ void k_prep(const float* __restrict__ w, unsigned short* __restrict__ wt,
                       int K, int N, int Ka, int total) {
    int i = blockIdx.x * 256 + threadIdx.x;
    if (i >= total) return;
    int k = i / N, n = i - k * N;
    wt[(size_t)n * Ka + k] = f2bf(w[i]);
}

// ---------------- conv weight prep: (128,3,4,4) fp32 -> (128,64) bf16 (K padded) ----
__global__ void k_prepc(const float* __restrict__ w, unsigned short* __restrict__ wc) {
    int i = blockIdx.x * 256 + threadIdx.x;
    if (i >= 128 * 64) return;
    int ch = i >> 6, k = i & 63;
    wc[i] = (k < 48) ? f2bf(w[ch * 48 + k]) : (unsigned short)0;
}

// ---------------- MFMA conv 4x4/s4 + L2 normalize, channel-last bf16 out ----------------
#define APAD 72
__global__ __launch_bounds__(256) void k_conv(const float* __restrict__ video,
                                              const unsigned short* __restrict__ wc,
                                              const float* __restrict__ b,
                                              unsigned short* __restrict__ out) {
    __shared__ __align__(16) short As[128 * APAD];
    __shared__ __align__(16) short Bs[128 * APAD];
    const int y = blockIdx.x;
    const int tf = blockIdx.y;
    const int tid = threadIdx.x;

    {
        int pos = tid >> 1, half = tid & 1;
        short8 z = (short8){0,0,0,0,0,0,0,0};
        *(short8*)&As[pos * APAD + 48 + half * 8] = z;
    }
    #pragma unroll
    for (int s = 0; s < 6; ++s) {
        int chunk = s * 256 + tid;
        int c = chunk >> 9, r = chunk & 511;
        int ky = r >> 7, pos = r & 127;
        float4 v = *(const float4*)&video[(((size_t)(tf * 3 + c) * 384) + 4 * y + ky) * 512 + pos * 4];
        unsigned short o[4];
        o[0] = f2bf(v.x * (2.0f / 255.0f) - 1.0f);
        o[1] = f2bf(v.y * (2.0f / 255.0f) - 1.0f);
        o[2] = f2bf(v.z * (2.0f / 255.0f) - 1.0f);
        o[3] = f2bf(v.w * (2.0f / 255.0f) - 1.0f);
        *(uint2*)&As[pos * APAD + c * 16 + ky * 4] = *(const uint2*)o;
    }
    #pragma unroll
    for (int s = 0; s < 4; ++s) {
        int chunk = s * 256 + tid;
        int row = chunk >> 3, q = chunk & 7;
        *(uint4*)&Bs[row * APAD + q * 8] = *(const uint4*)&wc[row * 64 + q * 8];
    }
    __syncthreads();

    const int w = tid >> 6, lane = tid & 63, ml = lane & 15, quad = lane >> 4;
    f32x4 acc[2][8];
    #pragma unroll
    for (int mi = 0; mi < 2; ++mi)
        #pragma unroll
        for (int ni = 0; ni < 8; ++ni) acc[mi][ni] = (f32x4){0.f, 0.f, 0.f, 0.f};
    #pragma unroll
    for (int kk = 0; kk < 2; ++kk) {
        short8 af[2];
        #pragma unroll
        for (int mi = 0; mi < 2; ++mi)
            af[mi] = *(const short8*)&As[(w * 32 + mi * 16 + ml) * APAD + kk * 32 + quad * 8];
        #pragma unroll
        for (int ni = 0; ni < 8; ++ni) {
            short8 bv = *(const short8*)&Bs[(ni * 16 + ml) * APAD + kk * 32 + quad * 8];
            #pragma unroll
            for (int mi = 0; mi < 2; ++mi)
                acc[mi][ni] = __builtin_amdgcn_mfma_f32_16x16x32_bf16(af[mi], bv, acc[mi][ni], 0, 0, 0);
        }
    }
    float bias[8];
    #pragma unroll
    for (int ni = 0; ni < 8; ++ni) bias[ni] = b[ni * 16 + ml];
    unsigned short* obase = out + ((size_t)(tf * 96 + y) * 128) * 128;
    #pragma unroll
    for (int mi = 0; mi < 2; ++mi) {
        float s2[4];
        #pragma unroll
        for (int reg = 0; reg < 4; ++reg) {
            float s = 0.f;
            #pragma unroll
            for (int ni = 0; ni < 8; ++ni) {
                float v = acc[mi][ni][reg] + bias[ni];
                s = fmaf(v, v, s);
            }
            s += __shfl_xor(s, 1); s += __shfl_xor(s, 2);
            s += __shfl_xor(s, 4); s += __shfl_xor(s, 8);
            s2[reg] = rsqrtf(fmaxf(s, 1e-12f));
        }
        #pragma unroll
        for (int reg = 0; reg < 4; ++reg) {
            int pos = w * 32 + mi * 16 + quad * 4 + reg;
            #pragma unroll
            for (int ni = 0; ni < 8; ++ni)
                obase[(size_t)pos * 128 + ni * 16 + ml] = f2bf((acc[mi][ni][reg] + bias[ni]) * s2[reg]);
        }
    }
}

// ---------------- 2x2 avg pool, bf16, 8-channel vectorized ----------------
__global__ void k_pool(const unsigned short* __restrict__ in, unsigned short* __restrict__ out,
                       int Ho, int Wo, int total8) {
    int i = blockIdx.x * 256 + threadIdx.x;
    if (i >= total8) return;
    int c8 = i & 15;
    int rest = i >> 4;
    int x = rest % Wo; rest /= Wo;
    int y = rest % Ho;
    int bt = rest / Ho;
    int Wi = Wo * 2;
    const unsigned short* base = in + (size_t)bt * (Ho * 2) * Wi * 128;
    const unsigned short* p00 = base + ((size_t)(2 * y) * Wi + 2 * x) * 128 + c8 * 8;
    const unsigned short* p10 = base + ((size_t)(2 * y + 1) * Wi + 2 * x) * 128 + c8 * 8;
    unsigned short o[8];
    #pragma unroll
    for (int k = 0; k < 8; ++k)
        o[k] = f2bf(0.25f * (bf2f(p00[k]) + bf2f(p00[128 + k]) + bf2f(p10[k]) + bf2f(p10[128 + k])));
    unsigned short* dst = out + (size_t)i * 8;
    *(uint4*)dst = *(const uint4*)o;
}

// ---------------- template features: trilinear sample, 8-ch vectorized ----------------
__global__ __launch_bounds__(256) void k_template(const float* __restrict__ q,
    const unsigned short* __restrict__ p0, const unsigned short* __restrict__ p1,
    const unsigned short* __restrict__ p2, const unsigned short* __restrict__ p3,
    unsigned short* __restrict__ tfs) {
    __shared__ float gw[NSUP * 4];
    __shared__ int go[NSUP * 4];
    const int lvl = blockIdx.x >> 7;
    const int n = blockIdx.x & 127;
    const int tid = threadIdx.x;
    const unsigned short* fm; int Hi, Wi;
    if (lvl == 0)      { fm = p0; Hi = 96; Wi = 128; }
    else if (lvl == 1) { fm = p1; Hi = 48; Wi = 64; }
    else if (lvl == 2) { fm = p2; Hi = 24; Wi = 32; }
    else               { fm = p3; Hi = 12; Wi = 16; }
    float t = fminf(fmaxf(q[n * 3 + 0], 0.0f), (float)(T_FR - 1));
    float t0f = floorf(t);
    float wt = t - t0f;
    int t0 = (int)t0f, t1 = min(t0 + 1, T_FR - 1);
    if (tid < NSUP) {
        float inv = 1.0f / (float)(1 << lvl);
        float x = fminf(fmaxf(q[n * 3 + 1] * 0.25f * inv + (float)(tid / 7 - 3), 0.0f), (float)(Wi - 1));
        float y = fminf(fmaxf(q[n * 3 + 2] * 0.25f * inv + (float)(tid % 7 - 3), 0.0f), (float)(Hi - 1));
        float x0f = floorf(x), y0f = floorf(y);
        float wx = x - x0f, wy = y - y0f;
        int x0 = (int)x0f, y0 = (int)y0f;
        int x1 = min(x0 + 1, Wi - 1), y1 = min(y0 + 1, Hi - 1);
        gw[tid * 4 + 0] = (1 - wy) * (1 - wx);
        gw[tid * 4 + 1] = (1 - wy) * wx;
        gw[tid * 4 + 2] = wy * (1 - wx);
        gw[tid * 4 + 3] = wy * wx;
        go[tid * 4 + 0] = (y0 * Wi + x0) * 128;
        go[tid * 4 + 1] = (y0 * Wi + x1) * 128;
        go[tid * 4 + 2] = (y1 * Wi + x0) * 128;
        go[tid * 4 + 3] = (y1 * Wi + x1) * 128;
    }
    __syncthreads();
    size_t fs = (size_t)Hi * Wi * 128;
    const unsigned short* f0 = fm + (size_t)t0 * fs;
    const unsigned short* f1 = fm + (size_t)t1 * fs;
    unsigned short* obase = tfs + ((size_t)lvl * N_Q + n) * 64 * 128;
    #pragma unroll
    for (int s = 0; s < 4; ++s) {
        int i = s * 256 + tid;
        int p = i >> 4, c8 = i & 15;
        unsigned short o[8];
        if (p >= NSUP) {
            uint4 z = {0, 0, 0, 0};
            *(uint4*)&obase[(size_t)p * 128 + c8 * 8] = z;
            continue;
        }
        int o0 = go[p * 4 + 0] + c8 * 8, o1 = go[p * 4 + 1] + c8 * 8;
        int o2 = go[p * 4 + 2] + c8 * 8, o3 = go[p * 4 + 3] + c8 * 8;
        float w0 = gw[p * 4 + 0], w1 = gw[p * 4 + 1], w2 = gw[p * 4 + 2], w3 = gw[p * 4 + 3];
        uint4 a0 = *(const uint4*)&f0[o0], a1 = *(const uint4*)&f0[o1];
        uint4 a2 = *(const uint4*)&f0[o2], a3 = *(const uint4*)&f0[o3];
        uint4 b0 = *(const uint4*)&f1[o0], b1 = *(const uint4*)&f1[o1];
        uint4 b2 = *(const uint4*)&f1[o2], b3 = *(const uint4*)&f1[o3];
        const unsigned short* s0 = (const unsigned short*)&a0;
        const unsigned short* s1 = (const unsigned short*)&a1;
        const unsigned short* s2 = (const unsigned short*)&a2;
        const unsigned short* s3 = (const unsigned short*)&a3;
        const unsigned short* r0 = (const unsigned short*)&b0;
        const unsigned short* r1 = (const unsigned short*)&b1;
        const unsigned short* r2 = (const unsigned short*)&b2;
        const unsigned short* r3 = (const unsigned short*)&b3;
        #pragma unroll
        for (int j = 0; j < 8; ++j) {
            float v0 = w0 * bf2f(s0[j]) + w1 * bf2f(s1[j]) + w2 * bf2f(s2[j]) + w3 * bf2f(s3[j]);
            float v1 = w0 * bf2f(r0[j]) + w1 * bf2f(r1[j]) + w2 * bf2f(r2[j]) + w3 * bf2f(r3[j]);
            o[j] = f2bf(v0 * (1 - wt) + v1 * wt);
        }
        *(uint4*)&obase[(size_t)p * 128 + c8 * 8] = *(const uint4*)o;
    }
}

// ---------------- fused resample + 49x49 correlation via MFMA ----------------
// R11-proven staging (CPAD=136) + explicit gather batching: each thread issues ALL
// its tap loads (up to 4 items x 4 taps of uint4) before any compute, collapsing
// 3-4 serialized memory round-trips into one.
#define CPAD 136
__global__ __launch_bounds__(256) void k_corr(
    const unsigned short* __restrict__ p0, const unsigned short* __restrict__ p1,
    const unsigned short* __restrict__ p2, const unsigned short* __restrict__ p3,
    const unsigned short* __restrict__ tfs, const float* __restrict__ coords,
    unsigned short* __restrict__ cv) {
    __shared__ __align__(16) short tf_s[64 * CPAD];
    __shared__ __align__(16) short cf_s[64 * CPAD];
    __shared__ float gw[NSUP * 4];
    __shared__ int go[NSUP * 4];
    const int id = blockIdx.x;
    const int xcd = id & 7;
    const int j = id >> 3;
    const int lvl = j >> 8;
    const int bt = ((j >> 7) & 1) * 8 + xcd;
    const int n = j & 127;
    const int r = lvl * 2048 + bt * 128 + n;
    const int tid = threadIdx.x;

    const unsigned short* tsrc = tfs + ((size_t)lvl * N_Q + n) * 64 * 128;
    #pragma unroll
    for (int s = 0; s < 4; ++s) {
        int ch = s * 256 + tid;
        int row = ch >> 4, c8 = ch & 15;
        *(uint4*)&tf_s[row * CPAD + c8 * 8] = *(const uint4*)&tsrc[row * 128 + c8 * 8];
    }
    if (tid < 240) {
        int row = NSUP + tid / 16, c8 = tid % 16;
        uint4 z = {0, 0, 0, 0};
        *(uint4*)&cf_s[row * CPAD + c8 * 8] = z;
    }

    const unsigned short* fm; int Hi, Wi;
    if (lvl == 0)      { fm = p0; Hi = 96; Wi = 128; }
    else if (lvl == 1) { fm = p1; Hi = 48; Wi = 64; }
    else if (lvl == 2) { fm = p2; Hi = 24; Wi = 32; }
    else               { fm = p3; Hi = 12; Wi = 16; }
    if (tid < NSUP) {
        float inv = 1.0f / (float)(1 << lvl);
        float cx = coords[((size_t)bt * N_Q + n) * 2 + 0] * inv;
        float cy = coords[((size_t)bt * N_Q + n) * 2 + 1] * inv;
        float x = fminf(fmaxf(cx + (float)(tid / 7 - 3), 0.0f), (float)(Wi - 1));
        float y = fminf(fmaxf(cy + (float)(tid % 7 - 3), 0.0f), (float)(Hi - 1));
        float x0f = floorf(x), y0f = floorf(y);
        float wx = x - x0f, wy = y - y0f;
        int x0 = (int)x0f, y0 = (int)y0f;
        int x1 = min(x0 + 1, Wi - 1), y1 = min(y0 + 1, Hi - 1);
        gw[tid * 4 + 0] = (1 - wy) * (1 - wx);
        gw[tid * 4 + 1] = (1 - wy) * wx;
        gw[tid * 4 + 2] = wy * (1 - wx);
        gw[tid * 4 + 3] = wy * wx;
        go[tid * 4 + 0] = (y0 * Wi + x0) * 128;
        go[tid * 4 + 1] = (y0 * Wi + x1) * 128;
        go[tid * 4 + 2] = (y1 * Wi + x0) * 128;
        go[tid * 4 + 3] = (y1 * Wi + x1) * 128;
    }
    __syncthreads();

    // batched gather: issue all tap loads first, then compute.
    const unsigned short* fbase = fm + (size_t)bt * Hi * Wi * 128;
    uint4 tap[4][4];
    float wv[4][4];
    #pragma unroll
    for (int s = 0; s < 4; ++s) {
        int i = s * 256 + tid;
        if (i < NSUP * 16) {
            int p = i >> 4, c8 = i & 15;
            int off = c8 * 8;
            tap[s][0] = *(const uint4*)&fbase[go[p * 4 + 0] + off];
            tap[s][1] = *(const uint4*)&fbase[go[p * 4 + 1] + off];
            tap[s][2] = *(const uint4*)&fbase[go[p * 4 + 2] + off];
            tap[s][3] = *(const uint4*)&fbase[go[p * 4 + 3] + off];
            wv[s][0] = gw[p * 4 + 0]; wv[s][1] = gw[p * 4 + 1];
            wv[s][2] = gw[p * 4 + 2]; wv[s][3] = gw[p * 4 + 3];
        }
    }
    #pragma unroll
    for (int s = 0; s < 4; ++s) {
        int i = s * 256 + tid;
        if (i < NSUP * 16) {
            int p = i >> 4, c8 = i & 15;
            const unsigned short* s0 = (const unsigned short*)&tap[s][0];
            const unsigned short* s1 = (const unsigned short*)&tap[s][1];
            const unsigned short* s2 = (const unsigned short*)&tap[s][2];
            const unsigned short* s3 = (const unsigned short*)&tap[s][3];
            float w0 = wv[s][0], w1 = wv[s][1], w2 = wv[s][2], w3 = wv[s][3];
            unsigned short o[8];
            #pragma unroll
            for (int jj = 0; jj < 8; ++jj)
                o[jj] = f2bf(w0 * bf2f(s0[jj]) + w1 * bf2f(s1[jj]) + w2 * bf2f(s2[jj]) + w3 * bf2f(s3[jj]));
            *(uint4*)&cf_s[p * CPAD + c8 * 8] = *(const uint4*)o;
        }
    }
    __syncthreads();

    const int w = tid >> 6, lane = tid & 63, ml = lane & 15, quad = lane >> 4;
    f32x4 acc[4];
    #pragma unroll
    for (int ni = 0; ni < 4; ++ni) acc[ni] = (f32x4){0.f, 0.f, 0.f, 0.f};
    #pragma unroll
    for (int kk = 0; kk < 4; ++kk) {
        short8 a = *(const short8*)&cf_s[(w * 16 + ml) * CPAD + kk * 32 + quad * 8];
        #pragma unroll
        for (int ni = 0; ni < 4; ++ni) {
            short8 b = *(const short8*)&tf_s[(ni * 16 + ml) * CPAD + kk * 32 + quad * 8];
            acc[ni] = __builtin_amdgcn_mfma_f32_16x16x32_bf16(a, b, acc[ni], 0, 0, 0);
        }
    }
    unsigned short* crow = cv + (size_t)r * KCV;
    const int p_base = w * 16 + quad * 4;
    #pragma unroll
    for (int ni = 0; ni < 4; ++ni) {
        int q = ni * 16 + ml;
        if (q < NSUP && p_base < 52) {
            unsigned short o4[4];
            #pragma unroll
            for (int reg = 0; reg < 4; ++reg) o4[reg] = f2bf(acc[ni][reg]);
            *(uint2*)&crow[q * 52 + p_base] = *(const uint2*)o4;
        }
    }
    if (tid < 12) crow[2548 + tid] = 0;
}

// ---------------- fc1 K-split MFMA GEMM: 128x128 tile (wave 64x64 = m97 shape) ----------------
__global__ __launch_bounds__(256) void k_ms128(const unsigned short* __restrict__ A,
                                               const unsigned short* __restrict__ Wt,
                                               float* __restrict__ Pbase,
                                               int Ka, int nbn, int nbm, int N,
                                               int nsteps, int S, int M) {
    __shared__ __align__(16) short As[128 * 32];
    __shared__ __align__(16) short Bs[128 * 32];
    const int id = blockIdx.x;
    const int xcd = id & 7;
    const int j = id >> 3;
    const int mpx = nbm >> 3;
    const int sS = j % S;
    const int jj = j / S;
    const int n_blk = jj % nbn;
    const int m_blk = xcd * mpx + jj / nbn;
    const int gm0 = m_blk * 128, n0 = n_blk * 128;
    const int kb = sS * (nsteps / S), ke = kb + nsteps / S;
    const int tid = threadIdx.x;
    const int w = tid >> 6, lane = tid & 63, ml = lane & 15, quad = lane >> 4;
    const int wm = w >> 1, wn = w & 1;
    const int wbase = (tid & 192) * 16;
    f32x4 acc[4][4];
    #pragma unroll
    for (int mi = 0; mi < 4; ++mi)
        #pragma unroll
        for (int ni = 0; ni < 4; ++ni) acc[mi][ni] = (f32x4){0.f, 0.f, 0.f, 0.f};
    const unsigned short* gA = A + (size_t)gm0 * Ka;
    const unsigned short* gB = Wt + (size_t)n0 * Ka;
    for (int k0 = kb * 32; k0 < ke * 32; k0 += 32) {
        #pragma unroll
        for (int ss = 0; ss < 2; ++ss) {
            int chunk = ss * 256 + tid;
            int m = chunk >> 2, q = chunk & 3;
            async16(gA + (size_t)m * Ka + k0 + q * 8, (char*)As + ss * 4096 + wbase);
        }
        #pragma unroll
        for (int ss = 0; ss < 2; ++ss) {
            int chunk = ss * 256 + tid;
            int m = chunk >> 2, q = chunk & 3;
            async16(gB + (size_t)m * Ka + k0 + q * 8, (char*)Bs + ss * 4096 + wbase);
        }
        __syncthreads();
        short8 af[4], bfr[4];
        #pragma unroll
        for (int mi = 0; mi < 4; ++mi)
            af[mi] = *(const short8*)&As[(wm * 64 + mi * 16 + ml) * 32 + quad * 8];
        #pragma unroll
        for (int ni = 0; ni < 4; ++ni)
            bfr[ni] = *(const short8*)&Bs[(wn * 64 + ni * 16 + ml) * 32 + quad * 8];
        #pragma unroll
        for (int mi = 0; mi < 4; ++mi)
            #pragma unroll
            for (int ni = 0; ni < 4; ++ni)
                acc[mi][ni] = __builtin_amdgcn_mfma_f32_16x16x32_bf16(af[mi], bfr[ni], acc[mi][ni], 0, 0, 0);
        __syncthreads();
    }
    float* P = Pbase + (size_t)sS * M * N;
    #pragma unroll
    for (int mi = 0; mi < 4; ++mi) {
        #pragma unroll
        for (int ni = 0; ni < 4; ++ni) {
            int gn = n0 + wn * 64 + ni * 16 + ml;
            #pragma unroll
            for (int reg = 0; reg < 4; ++reg) {
                int gm = gm0 + wm * 64 + mi * 16 + quad * 4 + reg;
                P[(size_t)gm * N + gn] = acc[mi][ni][reg];
            }
        }
    }
}

// ---------------- fused: fc1 split-reduce (+bias+gelu) AND token assemble ----------------
__global__ __launch_bounds__(256) void k_redasm(const float* __restrict__ P,
                                                const float* __restrict__ bias,
                                                unsigned short* __restrict__ h1out,
                                                const float* __restrict__ coords,
                                                const float* __restrict__ vis,
                                                const float* __restrict__ conf,
                                                const float* __restrict__ te,
                                                unsigned short* __restrict__ x) {
    const int bid = blockIdx.x;
    const int tid = threadIdx.x;
    if (bid < 3072) {
        int i4 = bid * 256 + tid;
        const float4* Pv = (const float4*)P;
        float4 v = Pv[i4];
        #pragma unroll
        for (int s = 1; s < 4; ++s) {
            float4 u = Pv[(size_t)s * (8192 * 96) + i4];
            v.x += u.x; v.y += u.y; v.z += u.z; v.w += u.w;
        }
        const float4 b = *(const float4*)&bias[(i4 % 96) * 4];
        unsigned short o[4];
        o[0] = f2bf(geluf(v.x + b.x));
        o[1] = f2bf(geluf(v.y + b.y));
        o[2] = f2bf(geluf(v.z + b.z));
        o[3] = f2bf(geluf(v.w + b.w));
        *(uint2*)&h1out[(size_t)i4 * 4] = *(const uint2*)o;
        return;
    }
    int i = (bid - 3072) * 256 + tid;
    int r = i >> 7, dd = i & 127;
    int d = (dd < 2) ? dd : 1024 + dd;
    int t = r >> 7, n = r & 127;
    if (d >= DIN) { x[(size_t)r * KU + d] = 0; return; }
    float v;
    if (d == 0) v = vis[r];
    else if (d == 1) v = conf[r];
    else {
        int ddd = d - 1026;
        float c0x = coords[r * 2], c0y = coords[r * 2 + 1];
        float v4[4];
        if (t < T_FR - 1) {
            v4[0] = (c0x - coords[((t + 1) * N_Q + n) * 2 + 0]) * (1.0f / 128.0f);
            v4[1] = (c0y - coords[((t + 1) * N_Q + n) * 2 + 1]) * (1.0f / 96.0f);
        } else { v4[0] = 0.f; v4[1] = 0.f; }
        if (t > 0) {
            v4[2] = (c0x - coords[((t - 1) * N_Q + n) * 2 + 0]) * (1.0f / 128.0f);
            v4[3] = (c0y - coords[((t - 1) * N_Q + n) * 2 + 1]) * (1.0f / 96.0f);
        } else { v4[2] = 0.f; v4[3] = 0.f; }
        if (ddd < 4) v = v4[ddd];
        else if (ddd < 44) { int s = (ddd - 4) >> 2, k = (ddd - 4) & 3; v = sinf(v4[k] * (float)(1 << s)); }
        else               { int s = (ddd - 44) >> 2, k = (ddd - 44) & 3; v = cosf(v4[k] * (float)(1 << s)); }
    }
    x[(size_t)r * KU + d] = f2bf(v + te[t * DIN + d]);
}

// ---------------- staged bf16 MFMA GEMM, 64x64 tile, BK=32, double-buffered LDS ----------------
__global__ __launch_bounds__(256) void k_gdb(const unsigned short* __restrict__ A,
                                             const unsigned short* __restrict__ Wt,
                                             const float* __restrict__ bias,
                                             void* __restrict__ Cout,
                                             const float* __restrict__ te,
                                             int Ka, int nbn, int nbm, int ldc, int mode) {
    __shared__ __align__(16) short As[2][64 * 32];
    __shared__ __align__(16) short Bs[2][64 * 32];
    const int id = blockIdx.x;
    const int xcd = id & 7;
    const int j = id >> 3;
    const int mpx = nbm >> 3;
    const int m_blk = xcd * mpx + j / nbn;
    const int n_blk = j % nbn;
    const int gm0 = m_blk * 64, n0 = n_blk * 64;
    const int tid = threadIdx.x;
    const int w = tid >> 6, lane = tid & 63, ml = lane & 15, quad = lane >> 4;
    const int wm = w >> 1, wn = w & 1;
    const int sm = tid >> 2, sq = tid & 3;
    const int soff = sm * 32 + sq * 8;

    f32x4 acc[2][2];
    #pragma unroll
    for (int mi = 0; mi < 2; ++mi)
        #pragma unroll
        for (int ni = 0; ni < 2; ++ni) acc[mi][ni] = (f32x4){0.f, 0.f, 0.f, 0.f};

    const unsigned short* gA = A + (size_t)(gm0 + sm) * Ka + sq * 8;
    const unsigned short* gB = Wt + (size_t)(n0 + sm) * Ka + sq * 8;

    {
        uint4 ra = *(const uint4*)gA;
        uint4 rb = *(const uint4*)gB;
        *(uint4*)&As[0][soff] = ra;
        *(uint4*)&Bs[0][soff] = rb;
    }
    __syncthreads();

    const int nsteps = Ka >> 5;
    int cur = 0;
    for (int s = 0; s < nsteps; ++s) {
        uint4 ra, rb;
        if (s + 1 < nsteps) {
            ra = *(const uint4*)(gA + (s + 1) * 32);
            rb = *(const uint4*)(gB + (s + 1) * 32);
        }
        short8 af[2], bfr[2];
        #pragma unroll
        for (int mi = 0; mi < 2; ++mi)
            af[mi] = *(const short8*)&As[cur][(wm * 32 + mi * 16 + ml) * 32 + quad * 8];
        #pragma unroll
        for (int ni = 0; ni < 2; ++ni)
            bfr[ni] = *(const short8*)&Bs[cur][(wn * 32 + ni * 16 + ml) * 32 + quad * 8];
        #pragma unroll
        for (int mi = 0; mi < 2; ++mi)
            #pragma unroll
            for (int ni = 0; ni < 2; ++ni)
                acc[mi][ni] = __builtin_amdgcn_mfma_f32_16x16x32_bf16(af[mi], bfr[ni], acc[mi][ni], 0, 0, 0);
        if (s + 1 < nsteps) {
            __syncthreads();
            *(uint4*)&As[cur ^ 1][soff] = ra;
            *(uint4*)&Bs[cur ^ 1][soff] = rb;
            __syncthreads();
            cur ^= 1;
        }
    }

    #pragma unroll
    for (int mi = 0; mi < 2; ++mi) {
        #pragma unroll
        for (int ni = 0; ni < 2; ++ni) {
            int gn = n0 + wn * 32 + ni * 16 + ml;
            float bv = bias[gn];
            #pragma unroll
            for (int reg = 0; reg < 4; ++reg) {
                int gm = gm0 + wm * 32 + mi * 16 + quad * 4 + reg;
                float v = acc[mi][ni][reg] + bv;
                if (mode == 1) v = geluf(v);
                if (mode == 2) {
                    int row = gm & 2047, lvl = gm >> 11;
                    int d = 2 + lvl * 256 + gn;
                    int t = row >> 7;
                    ((unsigned short*)Cout)[(size_t)row * KU + d] = f2bf(v + te[t * DIN + d]);
                } else {
                    ((unsigned short*)Cout)[(size_t)gm * ldc + gn] = f2bf(v);
                }
            }
        }
    }
}

// ---------------- fused up2 + state update ----------------
__global__ __launch_bounds__(256) void k_up2(const unsigned short* __restrict__ h1,
                                             const float* __restrict__ w2,
                                             const float* __restrict__ b2,
                                             float* __restrict__ coords,
                                             float* __restrict__ vis,
                                             float* __restrict__ conf) {
    const int w = threadIdx.x >> 6, lane = threadIdx.x & 63;
    const int r = blockIdx.x * 4 + w;
    float a0 = 0.f, a1 = 0.f, a2 = 0.f, a3 = 0.f;
    if (lane < 48) {
        short8 av = *(const short8*)&h1[(size_t)r * 384 + lane * 8];
        const float* wp = w2 + lane * 32;
        #pragma unroll
        for (int j = 0; j < 8; ++j) {
            float x = bf2f((unsigned short)av[j]);
            a0 = fmaf(x, wp[j * 4 + 0], a0);
            a1 = fmaf(x, wp[j * 4 + 1], a1);
            a2 = fmaf(x, wp[j * 4 + 2], a2);
            a3 = fmaf(x, wp[j * 4 + 3], a3);
        }
    }
    #pragma unroll
    for (int m = 32; m > 0; m >>= 1) {
        a0 += __shfl_xor(a0, m); a1 += __shfl_xor(a1, m);
        a2 += __shfl_xor(a2, m); a3 += __shfl_xor(a3, m);
    }
    if (lane == 0) {
        coords[r * 2 + 0] += a0 + b2[0];
        coords[r * 2 + 1] += a1 + b2[1];
        vis[r] += a2 + b2[2];
        conf[r] += a3 + b2[3];
    }
}

// ---------------- final outputs ----------------
__global__ void k_output(const float* __restrict__ coords, const float* __restrict__ vis,
                         const float* __restrict__ conf, float* __restrict__ out) {
    int r = blockIdx.x * 256 + threadIdx.x;
    if (r >= T_FR * N_Q) return;
    out[r * 2 + 0] = coords[r * 2 + 0] * 4.0f;
    out[r * 2 + 1] = coords[r * 2 + 1] * 4.0f;
    out[4096 + r] = 1.0f / (1.0f + expf(-vis[r]));
    out[6144 + r] = 1.0f / (1.0f + expf(-conf[r]));
}

extern "C" void kernel_launch(void* const* d_in, const int* in_sizes, int n_in,
                              void* d_out, int out_size, void* d_ws, size_t ws_size,
                              hipStream_t stream) {
    const float* video   = (const float*)d_in[0];
    const float* queries = (const float*)d_in[1];
    const float* fnet_w  = (const float*)d_in[2];
    const float* fnet_b  = (const float*)d_in[3];
    const float* fc1_w   = (const float*)d_in[4];
    const float* fc1_b   = (const float*)d_in[5];
    const float* fc2_w   = (const float*)d_in[6];
    const float* fc2_b   = (const float*)d_in[7];
    const float* up_w1   = (const float*)d_in[8];
    const float* up_b1   = (const float*)d_in[9];
    const float* up_w2   = (const float*)d_in[10];
    const float* up_b2   = (const float*)d_in[11];
    const float* t_emb   = (const float*)d_in[12];

    char* wsb = (char*)d_ws;
    size_t off = 0;
    #define ALLOC_US(name, elems) unsigned short* name = (unsigned short*)(wsb + off); off += ((size_t)(elems) * 2 + 15) & ~15ull;
    #define ALLOC_F(name, elems)  float* name = (float*)(wsb + off); off += ((size_t)(elems) * 4 + 15) & ~15ull;
    ALLOC_US(pyr0, (size_t)16 * 96 * 128 * 128)
    ALLOC_US(pyr1, (size_t)16 * 48 * 64 * 128)
    ALLOC_US(pyr2, (size_t)16 * 24 * 32 * 128)
    ALLOC_US(pyr3, (size_t)16 * 12 * 16 * 128)
    ALLOC_US(tfs,  (size_t)4 * N_Q * 64 * 128)
    ALLOC_US(cv,   (size_t)8192 * KCV)
    ALLOC_US(h1,   (size_t)8192 * 384)
    ALLOC_US(xb,   (size_t)2048 * KU)
    ALLOC_US(wt1,  (size_t)384 * KCV)
    ALLOC_US(wt2,  (size_t)256 * 384)
    ALLOC_US(wtu,  (size_t)384 * KU)
    ALLOC_US(wcv,  (size_t)128 * 64)
    ALLOC_F(pp,   (size_t)4 * 8192 * 384)
    ALLOC_F(te,   (size_t)T_FR * DIN)
    ALLOC_F(crd,  (size_t)2048 * 2)
    ALLOC_F(vis,  2048)
    ALLOC_F(conf, 2048)

    k_te<<<(T_FR * DIN + 255) / 256, 256, 0, stream>>>(t_emb, te);
    k_init<<<8, 256, 0, stream>>>(queries, crd, vis, conf);
    hipMemsetAsync(wt1, 0, (size_t)384 * KCV * 2, stream);
    k_prep1<<<(2401 * 384 + 255) / 256, 256, 0, stream>>>(fc1_w, wt1);
    k_prep<<<(384 * 256 + 255) / 256, 256, 0, stream>>>(fc2_w, wt2, 384, 256, 384, 384 * 256);
    k_prep<<<(DIN * 384 + 255) / 256, 256, 0, stream>>>(up_w1, wtu, DIN, 384, KU, DIN * 384);
    k_prepc<<<32, 256, 0, stream>>>(fnet_w, wcv);
    k_conv<<<dim3(96, 16), 256, 0, stream>>>(video, wcv, fnet_b, pyr0);
    k_pool<<<(16 * 48 * 64 * 16 + 255) / 256, 256, 0, stream>>>(pyr0, pyr1, 48, 64, 16 * 48 * 64 * 16);
    k_pool<<<(16 * 24 * 32 * 16 + 255) / 256, 256, 0, stream>>>(pyr1, pyr2, 24, 32, 16 * 24 * 32 * 16);
    k_pool<<<(16 * 12 * 16 * 16 + 255) / 256, 256, 0, stream>>>(pyr2, pyr3, 12, 16, 16 * 12 * 16 * 16);
    k_template<<<4 * N_Q, 256, 0, stream>>>(queries, pyr0, pyr1, pyr2, pyr3, tfs);

    for (int it = 0; it < ITERS; ++it) {
        k_corr<<<8192, 256, 0, stream>>>(pyr0, pyr1, pyr2, pyr3, tfs, crd, cv);
        k_ms128<<<768, 256, 0, stream>>>(cv, wt1, pp, KCV, 3, 64, 384, 80, 4, 8192);
        k_redasm<<<4096, 256, 0, stream>>>(pp, fc1_b, h1, crd, vis, conf, te, xb);
        k_gdb<<<512, 256, 0, stream>>>(h1, wt2, fc2_b, xb, te, 384, 4, 128, 0, 2);
        k_gdb<<<192, 256, 0, stream>>>(xb, wtu, up_b1, h1, nullptr, KU, 6, 32, 384, 1);
        k_up2<<<512, 256, 0, stream>>>(h1, up_w2, up_b2, crd, vis, conf);
    }
    k_output<<<8, 256, 0, stream>>>(crd, vis, conf, (float*)d_out);
}

// Round 14
// 603.968 us; speedup vs baseline: 1.1785x; 1.1785x over previous
//
#include <hip/hip_runtime.h>
#include <math.h>

#define T_FR   16
#define N_Q    128
#define NSUP   49
#define H0     96
#define W0     128
#define DIN    1110
#define ITERS  4
#define KCV    2560   // cv K: q*52+p, q<49, p<52 (p>=49 exact zeros), tail 2548..2559 zero
#define KU     1152   // padded 1110 (multiple of 64)

typedef __attribute__((ext_vector_type(8))) short short8;
typedef __attribute__((ext_vector_type(4))) float f32x4;

__device__ __forceinline__ float geluf(float x) {
    return 0.5f * x * (1.0f + erff(x * 0.70710678118654752f));
}
__device__ __forceinline__ unsigned short f2bf(float f) {
    unsigned u = __float_as_uint(f);
    u += 0x7fff + ((u >> 16) & 1);
    return (unsigned short)(u >> 16);
}
__device__ __forceinline__ float bf2f(unsigned short s) {
    return __uint_as_float(((unsigned)s) << 16);
}
__device__ __forceinline__ void async16(const void* g, void* l) {
    __builtin_amdgcn_global_load_lds(
        (const __attribute__((address_space(1))) void*)g,
        (__attribute__((address_space(3))) void*)l, 16, 0, 0);
}

// ---------------- time embedding interpolation (50 -> 16) ----------------
__global__ void k_te(const float* __restrict__ emb, float* __restrict__ te) {
    int i = blockIdx.x * 256 + threadIdx.x;
    if (i >= T_FR * DIN) return;
    int t = i / DIN, d = i - t * DIN;
    float j = ((float)t + 0.5f) * (50.0f / 16.0f) - 0.5f;
    j = fminf(fmaxf(j, 0.0f), 49.0f);
    float j0f = floorf(j);
    int j0 = (int)j0f;
    int j1 = min(j0 + 1, 49);
    float w = j - j0f;
    te[i] = emb[j0 * DIN + d] * (1.0f - w) + emb[j1 * DIN + d] * w;
}

// ---------------- state init ----------------
__global__ void k_init(const float* __restrict__ q, float* __restrict__ coords,
                       float* __restrict__ vis, float* __restrict__ conf) {
    int r = blockIdx.x * 256 + threadIdx.x;
    if (r >= T_FR * N_Q) return;
    int n = r & 127;
    coords[r * 2 + 0] = q[n * 3 + 1] * 0.25f;
    coords[r * 2 + 1] = q[n * 3 + 2] * 0.25f;
    vis[r] = 0.0f;
    conf[r] = 0.0f;
}

// ---------------- fc1 weight prep: (2401,384) fp32 -> bf16 (384, KCV) permuted ----------------
__global__ void k_prep1(const float* __restrict__ w, unsigned short* __restrict__ wt) {
    int i = blockIdx.x * 256 + threadIdx.x;
    if (i >= 2401 * 384) return;
    int k = i / 384, n = i - k * 384;
    int p = k / 49, q = k - p * 49;
    wt[(size_t)n * KCV + q * 52 + p] = f2bf(w[i]);
}

// ---------------- generic weight prep: fp32 (K,N) -> bf16 transposed (N,Ka) ----------------
__global__ void k_prep(const float* __restrict__ w, unsigned short* __restrict__ wt,
                       int K, int N, int Ka, int total) {
    int i = blockIdx.x * 256 + threadIdx.x;
    if (i >= total) return;
    int k = i / N, n = i - k * N;
    wt[(size_t)n * Ka + k] = f2bf(w[i]);
}

// ---------------- conv weight prep: (128,3,4,4) fp32 -> (128,64) bf16 (K padded) ----
__global__ void k_prepc(const float* __restrict__ w, unsigned short* __restrict__ wc) {
    int i = blockIdx.x * 256 + threadIdx.x;
    if (i >= 128 * 64) return;
    int ch = i >> 6, k = i & 63;
    wc[i] = (k < 48) ? f2bf(w[ch * 48 + k]) : (unsigned short)0;
}

// ---------------- MFMA conv 4x4/s4 + L2 normalize, channel-last bf16 out ----------------
#define APAD 72
__global__ __launch_bounds__(256) void k_conv(const float* __restrict__ video,
                                              const unsigned short* __restrict__ wc,
                                              const float* __restrict__ b,
                                              unsigned short* __restrict__ out) {
    __shared__ __align__(16) short As[128 * APAD];
    __shared__ __align__(16) short Bs[128 * APAD];
    const int y = blockIdx.x;
    const int tf = blockIdx.y;
    const int tid = threadIdx.x;

    {
        int pos = tid >> 1, half = tid & 1;
        short8 z = (short8){0,0,0,0,0,0,0,0};
        *(short8*)&As[pos * APAD + 48 + half * 8] = z;
    }
    #pragma unroll
    for (int s = 0; s < 6; ++s) {
        int chunk = s * 256 + tid;
        int c = chunk >> 9, r = chunk & 511;
        int ky = r >> 7, pos = r & 127;
        float4 v = *(const float4*)&video[(((size_t)(tf * 3 + c) * 384) + 4 * y + ky) * 512 + pos * 4];
        unsigned short o[4];
        o[0] = f2bf(v.x * (2.0f / 255.0f) - 1.0f);
        o[1] = f2bf(v.y * (2.0f / 255.0f) - 1.0f);
        o[2] = f2bf(v.z * (2.0f / 255.0f) - 1.0f);
        o[3] = f2bf(v.w * (2.0f / 255.0f) - 1.0f);
        *(uint2*)&As[pos * APAD + c * 16 + ky * 4] = *(const uint2*)o;
    }
    #pragma unroll
    for (int s = 0; s < 4; ++s) {
        int chunk = s * 256 + tid;
        int row = chunk >> 3, q = chunk & 7;
        *(uint4*)&Bs[row * APAD + q * 8] = *(const uint4*)&wc[row * 64 + q * 8];
    }
    __syncthreads();

    const int w = tid >> 6, lane = tid & 63, ml = lane & 15, quad = lane >> 4;
    f32x4 acc[2][8];
    #pragma unroll
    for (int mi = 0; mi < 2; ++mi)
        #pragma unroll
        for (int ni = 0; ni < 8; ++ni) acc[mi][ni] = (f32x4){0.f, 0.f, 0.f, 0.f};
    #pragma unroll
    for (int kk = 0; kk < 2; ++kk) {
        short8 af[2];
        #pragma unroll
        for (int mi = 0; mi < 2; ++mi)
            af[mi] = *(const short8*)&As[(w * 32 + mi * 16 + ml) * APAD + kk * 32 + quad * 8];
        #pragma unroll
        for (int ni = 0; ni < 8; ++ni) {
            short8 bv = *(const short8*)&Bs[(ni * 16 + ml) * APAD + kk * 32 + quad * 8];
            #pragma unroll
            for (int mi = 0; mi < 2; ++mi)
                acc[mi][ni] = __builtin_amdgcn_mfma_f32_16x16x32_bf16(af[mi], bv, acc[mi][ni], 0, 0, 0);
        }
    }
    float bias[8];
    #pragma unroll
    for (int ni = 0; ni < 8; ++ni) bias[ni] = b[ni * 16 + ml];
    unsigned short* obase = out + ((size_t)(tf * 96 + y) * 128) * 128;
    #pragma unroll
    for (int mi = 0; mi < 2; ++mi) {
        float s2[4];
        #pragma unroll
        for (int reg = 0; reg < 4; ++reg) {
            float s = 0.f;
            #pragma unroll
            for (int ni = 0; ni < 8; ++ni) {
                float v = acc[mi][ni][reg] + bias[ni];
                s = fmaf(v, v, s);
            }
            s += __shfl_xor(s, 1); s += __shfl_xor(s, 2);
            s += __shfl_xor(s, 4); s += __shfl_xor(s, 8);
            s2[reg] = rsqrtf(fmaxf(s, 1e-12f));
        }
        #pragma unroll
        for (int reg = 0; reg < 4; ++reg) {
            int pos = w * 32 + mi * 16 + quad * 4 + reg;
            #pragma unroll
            for (int ni = 0; ni < 8; ++ni)
                obase[(size_t)pos * 128 + ni * 16 + ml] = f2bf((acc[mi][ni][reg] + bias[ni]) * s2[reg]);
        }
    }
}

// ---------------- 2x2 avg pool, bf16, 8-channel vectorized ----------------
__global__ void k_pool(const unsigned short* __restrict__ in, unsigned short* __restrict__ out,
                       int Ho, int Wo, int total8) {
    int i = blockIdx.x * 256 + threadIdx.x;
    if (i >= total8) return;
    int c8 = i & 15;
    int rest = i >> 4;
    int x = rest % Wo; rest /= Wo;
    int y = rest % Ho;
    int bt = rest / Ho;
    int Wi = Wo * 2;
    const unsigned short* base = in + (size_t)bt * (Ho * 2) * Wi * 128;
    const unsigned short* p00 = base + ((size_t)(2 * y) * Wi + 2 * x) * 128 + c8 * 8;
    const unsigned short* p10 = base + ((size_t)(2 * y + 1) * Wi + 2 * x) * 128 + c8 * 8;
    unsigned short o[8];
    #pragma unroll
    for (int k = 0; k < 8; ++k)
        o[k] = f2bf(0.25f * (bf2f(p00[k]) + bf2f(p00[128 + k]) + bf2f(p10[k]) + bf2f(p10[128 + k])));
    unsigned short* dst = out + (size_t)i * 8;
    *(uint4*)dst = *(const uint4*)o;
}

// ---------------- template features: trilinear sample, 8-ch vectorized ----------------
__global__ __launch_bounds__(256) void k_template(const float* __restrict__ q,
    const unsigned short* __restrict__ p0, const unsigned short* __restrict__ p1,
    const unsigned short* __restrict__ p2, const unsigned short* __restrict__ p3,
    unsigned short* __restrict__ tfs) {
    __shared__ float gw[NSUP * 4];
    __shared__ int go[NSUP * 4];
    const int lvl = blockIdx.x >> 7;
    const int n = blockIdx.x & 127;
    const int tid = threadIdx.x;
    const unsigned short* fm; int Hi, Wi;
    if (lvl == 0)      { fm = p0; Hi = 96; Wi = 128; }
    else if (lvl == 1) { fm = p1; Hi = 48; Wi = 64; }
    else if (lvl == 2) { fm = p2; Hi = 24; Wi = 32; }
    else               { fm = p3; Hi = 12; Wi = 16; }
    float t = fminf(fmaxf(q[n * 3 + 0], 0.0f), (float)(T_FR - 1));
    float t0f = floorf(t);
    float wt = t - t0f;
    int t0 = (int)t0f, t1 = min(t0 + 1, T_FR - 1);
    if (tid < NSUP) {
        float inv = 1.0f / (float)(1 << lvl);
        float x = fminf(fmaxf(q[n * 3 + 1] * 0.25f * inv + (float)(tid / 7 - 3), 0.0f), (float)(Wi - 1));
        float y = fminf(fmaxf(q[n * 3 + 2] * 0.25f * inv + (float)(tid % 7 - 3), 0.0f), (float)(Hi - 1));
        float x0f = floorf(x), y0f = floorf(y);
        float wx = x - x0f, wy = y - y0f;
        int x0 = (int)x0f, y0 = (int)y0f;
        int x1 = min(x0 + 1, Wi - 1), y1 = min(y0 + 1, Hi - 1);
        gw[tid * 4 + 0] = (1 - wy) * (1 - wx);
        gw[tid * 4 + 1] = (1 - wy) * wx;
        gw[tid * 4 + 2] = wy * (1 - wx);
        gw[tid * 4 + 3] = wy * wx;
        go[tid * 4 + 0] = (y0 * Wi + x0) * 128;
        go[tid * 4 + 1] = (y0 * Wi + x1) * 128;
        go[tid * 4 + 2] = (y1 * Wi + x0) * 128;
        go[tid * 4 + 3] = (y1 * Wi + x1) * 128;
    }
    __syncthreads();
    size_t fs = (size_t)Hi * Wi * 128;
    const unsigned short* f0 = fm + (size_t)t0 * fs;
    const unsigned short* f1 = fm + (size_t)t1 * fs;
    unsigned short* obase = tfs + ((size_t)lvl * N_Q + n) * 64 * 128;
    #pragma unroll
    for (int s = 0; s < 4; ++s) {
        int i = s * 256 + tid;
        int p = i >> 4, c8 = i & 15;
        unsigned short o[8];
        if (p >= NSUP) {
            uint4 z = {0, 0, 0, 0};
            *(uint4*)&obase[(size_t)p * 128 + c8 * 8] = z;
            continue;
        }
        int o0 = go[p * 4 + 0] + c8 * 8, o1 = go[p * 4 + 1] + c8 * 8;
        int o2 = go[p * 4 + 2] + c8 * 8, o3 = go[p * 4 + 3] + c8 * 8;
        float w0 = gw[p * 4 + 0], w1 = gw[p * 4 + 1], w2 = gw[p * 4 + 2], w3 = gw[p * 4 + 3];
        uint4 a0 = *(const uint4*)&f0[o0], a1 = *(const uint4*)&f0[o1];
        uint4 a2 = *(const uint4*)&f0[o2], a3 = *(const uint4*)&f0[o3];
        uint4 b0 = *(const uint4*)&f1[o0], b1 = *(const uint4*)&f1[o1];
        uint4 b2 = *(const uint4*)&f1[o2], b3 = *(const uint4*)&f1[o3];
        const unsigned short* s0 = (const unsigned short*)&a0;
        const unsigned short* s1 = (const unsigned short*)&a1;
        const unsigned short* s2 = (const unsigned short*)&a2;
        const unsigned short* s3 = (const unsigned short*)&a3;
        const unsigned short* r0 = (const unsigned short*)&b0;
        const unsigned short* r1 = (const unsigned short*)&b1;
        const unsigned short* r2 = (const unsigned short*)&b2;
        const unsigned short* r3 = (const unsigned short*)&b3;
        #pragma unroll
        for (int j = 0; j < 8; ++j) {
            float v0 = w0 * bf2f(s0[j]) + w1 * bf2f(s1[j]) + w2 * bf2f(s2[j]) + w3 * bf2f(s3[j]);
            float v1 = w0 * bf2f(r0[j]) + w1 * bf2f(r1[j]) + w2 * bf2f(r2[j]) + w3 * bf2f(r3[j]);
            o[j] = f2bf(v0 * (1 - wt) + v1 * wt);
        }
        *(uint4*)&obase[(size_t)p * 128 + c8 * 8] = *(const uint4*)o;
    }
}

// ---------------- fused resample + 49x49 correlation via MFMA (R11-proven) ----------------
#define CPAD 136
__global__ __launch_bounds__(256) void k_corr(
    const unsigned short* __restrict__ p0, const unsigned short* __restrict__ p1,
    const unsigned short* __restrict__ p2, const unsigned short* __restrict__ p3,
    const unsigned short* __restrict__ tfs, const float* __restrict__ coords,
    unsigned short* __restrict__ cv) {
    __shared__ __align__(16) short tf_s[64 * CPAD];
    __shared__ __align__(16) short cf_s[64 * CPAD];
    __shared__ float gw[NSUP * 4];
    __shared__ int go[NSUP * 4];
    const int id = blockIdx.x;
    const int xcd = id & 7;
    const int j = id >> 3;
    const int lvl = j >> 8;
    const int bt = ((j >> 7) & 1) * 8 + xcd;
    const int n = j & 127;
    const int r = lvl * 2048 + bt * 128 + n;
    const int tid = threadIdx.x;

    const unsigned short* tsrc = tfs + ((size_t)lvl * N_Q + n) * 64 * 128;
    #pragma unroll
    for (int s = 0; s < 4; ++s) {
        int ch = s * 256 + tid;
        int row = ch >> 4, c8 = ch & 15;
        *(uint4*)&tf_s[row * CPAD + c8 * 8] = *(const uint4*)&tsrc[row * 128 + c8 * 8];
    }
    if (tid < 240) {
        int row = NSUP + tid / 16, c8 = tid % 16;
        uint4 z = {0, 0, 0, 0};
        *(uint4*)&cf_s[row * CPAD + c8 * 8] = z;
    }

    const unsigned short* fm; int Hi, Wi;
    if (lvl == 0)      { fm = p0; Hi = 96; Wi = 128; }
    else if (lvl == 1) { fm = p1; Hi = 48; Wi = 64; }
    else if (lvl == 2) { fm = p2; Hi = 24; Wi = 32; }
    else               { fm = p3; Hi = 12; Wi = 16; }
    if (tid < NSUP) {
        float inv = 1.0f / (float)(1 << lvl);
        float cx = coords[((size_t)bt * N_Q + n) * 2 + 0] * inv;
        float cy = coords[((size_t)bt * N_Q + n) * 2 + 1] * inv;
        float x = fminf(fmaxf(cx + (float)(tid / 7 - 3), 0.0f), (float)(Wi - 1));
        float y = fminf(fmaxf(cy + (float)(tid % 7 - 3), 0.0f), (float)(Hi - 1));
        float x0f = floorf(x), y0f = floorf(y);
        float wx = x - x0f, wy = y - y0f;
        int x0 = (int)x0f, y0 = (int)y0f;
        int x1 = min(x0 + 1, Wi - 1), y1 = min(y0 + 1, Hi - 1);
        gw[tid * 4 + 0] = (1 - wy) * (1 - wx);
        gw[tid * 4 + 1] = (1 - wy) * wx;
        gw[tid * 4 + 2] = wy * (1 - wx);
        gw[tid * 4 + 3] = wy * wx;
        go[tid * 4 + 0] = (y0 * Wi + x0) * 128;
        go[tid * 4 + 1] = (y0 * Wi + x1) * 128;
        go[tid * 4 + 2] = (y1 * Wi + x0) * 128;
        go[tid * 4 + 3] = (y1 * Wi + x1) * 128;
    }
    __syncthreads();

    const unsigned short* fbase = fm + (size_t)bt * Hi * Wi * 128;
    for (int i = tid; i < NSUP * 16; i += 256) {
        int p = i >> 4, c8 = i & 15;
        int o0 = go[p * 4 + 0] + c8 * 8, o1 = go[p * 4 + 1] + c8 * 8;
        int o2 = go[p * 4 + 2] + c8 * 8, o3 = go[p * 4 + 3] + c8 * 8;
        float w0 = gw[p * 4 + 0], w1 = gw[p * 4 + 1], w2 = gw[p * 4 + 2], w3 = gw[p * 4 + 3];
        uint4 a0 = *(const uint4*)&fbase[o0], a1 = *(const uint4*)&fbase[o1];
        uint4 a2 = *(const uint4*)&fbase[o2], a3 = *(const uint4*)&fbase[o3];
        const unsigned short* s0 = (const unsigned short*)&a0;
        const unsigned short* s1 = (const unsigned short*)&a1;
        const unsigned short* s2 = (const unsigned short*)&a2;
        const unsigned short* s3 = (const unsigned short*)&a3;
        unsigned short o[8];
        #pragma unroll
        for (int jj = 0; jj < 8; ++jj)
            o[jj] = f2bf(w0 * bf2f(s0[jj]) + w1 * bf2f(s1[jj]) + w2 * bf2f(s2[jj]) + w3 * bf2f(s3[jj]));
        *(uint4*)&cf_s[p * CPAD + c8 * 8] = *(const uint4*)o;
    }
    __syncthreads();

    const int w = tid >> 6, lane = tid & 63, ml = lane & 15, quad = lane >> 4;
    f32x4 acc[4];
    #pragma unroll
    for (int ni = 0; ni < 4; ++ni) acc[ni] = (f32x4){0.f, 0.f, 0.f, 0.f};
    #pragma unroll
    for (int kk = 0; kk < 4; ++kk) {
        short8 a = *(const short8*)&cf_s[(w * 16 + ml) * CPAD + kk * 32 + quad * 8];
        #pragma unroll
        for (int ni = 0; ni < 4; ++ni) {
            short8 b = *(const short8*)&tf_s[(ni * 16 + ml) * CPAD + kk * 32 + quad * 8];
            acc[ni] = __builtin_amdgcn_mfma_f32_16x16x32_bf16(a, b, acc[ni], 0, 0, 0);
        }
    }
    unsigned short* crow = cv + (size_t)r * KCV;
    const int p_base = w * 16 + quad * 4;
    #pragma unroll
    for (int ni = 0; ni < 4; ++ni) {
        int q = ni * 16 + ml;
        if (q < NSUP && p_base < 52) {
            unsigned short o4[4];
            #pragma unroll
            for (int reg = 0; reg < 4; ++reg) o4[reg] = f2bf(acc[ni][reg]);
            *(uint2*)&crow[q * 52 + p_base] = *(const uint2*)o4;
        }
    }
    if (tid < 12) crow[2548 + tid] = 0;
}

// ---------------- fc1 K-split MFMA GEMM: 128x128 tile (wave 64x64 = m97 shape) ----------------
__global__ __launch_bounds__(256) void k_ms128(const unsigned short* __restrict__ A,
                                               const unsigned short* __restrict__ Wt,
                                               float* __restrict__ Pbase,
                                               int Ka, int nbn, int nbm, int N,
                                               int nsteps, int S, int M) {
    __shared__ __align__(16) short As[128 * 32];
    __shared__ __align__(16) short Bs[128 * 32];
    const int id = blockIdx.x;
    const int xcd = id & 7;
    const int j = id >> 3;
    const int mpx = nbm >> 3;
    const int sS = j % S;
    const int jj = j / S;
    const int n_blk = jj % nbn;
    const int m_blk = xcd * mpx + jj / nbn;
    const int gm0 = m_blk * 128, n0 = n_blk * 128;
    const int kb = sS * (nsteps / S), ke = kb + nsteps / S;
    const int tid = threadIdx.x;
    const int w = tid >> 6, lane = tid & 63, ml = lane & 15, quad = lane >> 4;
    const int wm = w >> 1, wn = w & 1;
    const int wbase = (tid & 192) * 16;
    f32x4 acc[4][4];
    #pragma unroll
    for (int mi = 0; mi < 4; ++mi)
        #pragma unroll
        for (int ni = 0; ni < 4; ++ni) acc[mi][ni] = (f32x4){0.f, 0.f, 0.f, 0.f};
    const unsigned short* gA = A + (size_t)gm0 * Ka;
    const unsigned short* gB = Wt + (size_t)n0 * Ka;
    for (int k0 = kb * 32; k0 < ke * 32; k0 += 32) {
        #pragma unroll
        for (int ss = 0; ss < 2; ++ss) {
            int chunk = ss * 256 + tid;
            int m = chunk >> 2, q = chunk & 3;
            async16(gA + (size_t)m * Ka + k0 + q * 8, (char*)As + ss * 4096 + wbase);
        }
        #pragma unroll
        for (int ss = 0; ss < 2; ++ss) {
            int chunk = ss * 256 + tid;
            int m = chunk >> 2, q = chunk & 3;
            async16(gB + (size_t)m * Ka + k0 + q * 8, (char*)Bs + ss * 4096 + wbase);
        }
        __syncthreads();
        short8 af[4], bfr[4];
        #pragma unroll
        for (int mi = 0; mi < 4; ++mi)
            af[mi] = *(const short8*)&As[(wm * 64 + mi * 16 + ml) * 32 + quad * 8];
        #pragma unroll
        for (int ni = 0; ni < 4; ++ni)
            bfr[ni] = *(const short8*)&Bs[(wn * 64 + ni * 16 + ml) * 32 + quad * 8];
        #pragma unroll
        for (int mi = 0; mi < 4; ++mi)
            #pragma unroll
            for (int ni = 0; ni < 4; ++ni)
                acc[mi][ni] = __builtin_amdgcn_mfma_f32_16x16x32_bf16(af[mi], bfr[ni], acc[mi][ni], 0, 0, 0);
        __syncthreads();
    }
    float* P = Pbase + (size_t)sS * M * N;
    #pragma unroll
    for (int mi = 0; mi < 4; ++mi) {
        #pragma unroll
        for (int ni = 0; ni < 4; ++ni) {
            int gn = n0 + wn * 64 + ni * 16 + ml;
            #pragma unroll
            for (int reg = 0; reg < 4; ++reg) {
                int gm = gm0 + wm * 64 + mi * 16 + quad * 4 + reg;
                P[(size_t)gm * N + gn] = acc[mi][ni][reg];
            }
        }
    }
}

// ---------------- fused: fc1 split-reduce (+bias+gelu) AND token assemble ----------------
__global__ __launch_bounds__(256) void k_redasm(const float* __restrict__ P,
                                                const float* __restrict__ bias,
                                                unsigned short* __restrict__ h1out,
                                                const float* __restrict__ coords,
                                                const float* __restrict__ vis,
                                                const float* __restrict__ conf,
                                                const float* __restrict__ te,
                                                unsigned short* __restrict__ x) {
    const int bid = blockIdx.x;
    const int tid = threadIdx.x;
    if (bid < 3072) {
        int i4 = bid * 256 + tid;
        const float4* Pv = (const float4*)P;
        float4 v = Pv[i4];
        #pragma unroll
        for (int s = 1; s < 4; ++s) {
            float4 u = Pv[(size_t)s * (8192 * 96) + i4];
            v.x += u.x; v.y += u.y; v.z += u.z; v.w += u.w;
        }
        const float4 b = *(const float4*)&bias[(i4 % 96) * 4];
        unsigned short o[4];
        o[0] = f2bf(geluf(v.x + b.x));
        o[1] = f2bf(geluf(v.y + b.y));
        o[2] = f2bf(geluf(v.z + b.z));
        o[3] = f2bf(geluf(v.w + b.w));
        *(uint2*)&h1out[(size_t)i4 * 4] = *(const uint2*)o;
        return;
    }
    int i = (bid - 3072) * 256 + tid;
    int r = i >> 7, dd = i & 127;
    int d = (dd < 2) ? dd : 1024 + dd;
    int t = r >> 7, n = r & 127;
    if (d >= DIN) { x[(size_t)r * KU + d] = 0; return; }
    float v;
    if (d == 0) v = vis[r];
    else if (d == 1) v = conf[r];
    else {
        int ddd = d - 1026;
        float c0x = coords[r * 2], c0y = coords[r * 2 + 1];
        float v4[4];
        if (t < T_FR - 1) {
            v4[0] = (c0x - coords[((t + 1) * N_Q + n) * 2 + 0]) * (1.0f / 128.0f);
            v4[1] = (c0y - coords[((t + 1) * N_Q + n) * 2 + 1]) * (1.0f / 96.0f);
        } else { v4[0] = 0.f; v4[1] = 0.f; }
        if (t > 0) {
            v4[2] = (c0x - coords[((t - 1) * N_Q + n) * 2 + 0]) * (1.0f / 128.0f);
            v4[3] = (c0y - coords[((t - 1) * N_Q + n) * 2 + 1]) * (1.0f / 96.0f);
        } else { v4[2] = 0.f; v4[3] = 0.f; }
        if (ddd < 4) v = v4[ddd];
        else if (ddd < 44) { int s = (ddd - 4) >> 2, k = (ddd - 4) & 3; v = sinf(v4[k] * (float)(1 << s)); }
        else               { int s = (ddd - 44) >> 2, k = (ddd - 44) & 3; v = cosf(v4[k] * (float)(1 << s)); }
    }
    x[(size_t)r * KU + d] = f2bf(v + te[t * DIN + d]);
}

// ---------------- staged bf16 MFMA GEMM, 64x64 tile, BK=32, double-buffered LDS ----------------
__global__ __launch_bounds__(256) void k_gdb(const unsigned short* __restrict__ A,
                                             const unsigned short* __restrict__ Wt,
                                             const float* __restrict__ bias,
                                             void* __restrict__ Cout,
                                             const float* __restrict__ te,
                                             int Ka, int nbn, int nbm, int ldc, int mode) {
    __shared__ __align__(16) short As[2][64 * 32];
    __shared__ __align__(16) short Bs[2][64 * 32];
    const int id = blockIdx.x;
    const int xcd = id & 7;
    const int j = id >> 3;
    const int mpx = nbm >> 3;
    const int m_blk = xcd * mpx + j / nbn;
    const int n_blk = j % nbn;
    const int gm0 = m_blk * 64, n0 = n_blk * 64;
    const int tid = threadIdx.x;
    const int w = tid >> 6, lane = tid & 63, ml = lane & 15, quad = lane >> 4;
    const int wm = w >> 1, wn = w & 1;
    const int sm = tid >> 2, sq = tid & 3;
    const int soff = sm * 32 + sq * 8;

    f32x4 acc[2][2];
    #pragma unroll
    for (int mi = 0; mi < 2; ++mi)
        #pragma unroll
        for (int ni = 0; ni < 2; ++ni) acc[mi][ni] = (f32x4){0.f, 0.f, 0.f, 0.f};

    const unsigned short* gA = A + (size_t)(gm0 + sm) * Ka + sq * 8;
    const unsigned short* gB = Wt + (size_t)(n0 + sm) * Ka + sq * 8;

    {
        uint4 ra = *(const uint4*)gA;
        uint4 rb = *(const uint4*)gB;
        *(uint4*)&As[0][soff] = ra;
        *(uint4*)&Bs[0][soff] = rb;
    }
    __syncthreads();

    const int nsteps = Ka >> 5;
    int cur = 0;
    for (int s = 0; s < nsteps; ++s) {
        uint4 ra, rb;
        if (s + 1 < nsteps) {
            ra = *(const uint4*)(gA + (s + 1) * 32);
            rb = *(const uint4*)(gB + (s + 1) * 32);
        }
        short8 af[2], bfr[2];
        #pragma unroll
        for (int mi = 0; mi < 2; ++mi)
            af[mi] = *(const short8*)&As[cur][(wm * 32 + mi * 16 + ml) * 32 + quad * 8];
        #pragma unroll
        for (int ni = 0; ni < 2; ++ni)
            bfr[ni] = *(const short8*)&Bs[cur][(wn * 32 + ni * 16 + ml) * 32 + quad * 8];
        #pragma unroll
        for (int mi = 0; mi < 2; ++mi)
            #pragma unroll
            for (int ni = 0; ni < 2; ++ni)
                acc[mi][ni] = __builtin_amdgcn_mfma_f32_16x16x32_bf16(af[mi], bfr[ni], acc[mi][ni], 0, 0, 0);
        if (s + 1 < nsteps) {
            __syncthreads();
            *(uint4*)&As[cur ^ 1][soff] = ra;
            *(uint4*)&Bs[cur ^ 1][soff] = rb;
            __syncthreads();
            cur ^= 1;
        }
    }

    #pragma unroll
    for (int mi = 0; mi < 2; ++mi) {
        #pragma unroll
        for (int ni = 0; ni < 2; ++ni) {
            int gn = n0 + wn * 32 + ni * 16 + ml;
            float bv = bias[gn];
            #pragma unroll
            for (int reg = 0; reg < 4; ++reg) {
                int gm = gm0 + wm * 32 + mi * 16 + quad * 4 + reg;
                float v = acc[mi][ni][reg] + bv;
                if (mode == 1) v = geluf(v);
                if (mode == 2) {
                    int row = gm & 2047, lvl = gm >> 11;
                    int d = 2 + lvl * 256 + gn;
                    int t = row >> 7;
                    ((unsigned short*)Cout)[(size_t)row * KU + d] = f2bf(v + te[t * DIN + d]);
                } else {
                    ((unsigned short*)Cout)[(size_t)gm * ldc + gn] = f2bf(v);
                }
            }
        }
    }
}

// ---------------- fused up2 + state update ----------------
__global__ __launch_bounds__(256) void k_up2(const unsigned short* __restrict__ h1,
                                             const float* __restrict__ w2,
                                             const float* __restrict__ b2,
                                             float* __restrict__ coords,
                                             float* __restrict__ vis,
                                             float* __restrict__ conf) {
    const int w = threadIdx.x >> 6, lane = threadIdx.x & 63;
    const int r = blockIdx.x * 4 + w;
    float a0 = 0.f, a1 = 0.f, a2 = 0.f, a3 = 0.f;
    if (lane < 48) {
        short8 av = *(const short8*)&h1[(size_t)r * 384 + lane * 8];
        const float* wp = w2 + lane * 32;
        #pragma unroll
        for (int j = 0; j < 8; ++j) {
            float x = bf2f((unsigned short)av[j]);
            a0 = fmaf(x, wp[j * 4 + 0], a0);
            a1 = fmaf(x, wp[j * 4 + 1], a1);
            a2 = fmaf(x, wp[j * 4 + 2], a2);
            a3 = fmaf(x, wp[j * 4 + 3], a3);
        }
    }
    #pragma unroll
    for (int m = 32; m > 0; m >>= 1) {
        a0 += __shfl_xor(a0, m); a1 += __shfl_xor(a1, m);
        a2 += __shfl_xor(a2, m); a3 += __shfl_xor(a3, m);
    }
    if (lane == 0) {
        coords[r * 2 + 0] += a0 + b2[0];
        coords[r * 2 + 1] += a1 + b2[1];
        vis[r] += a2 + b2[2];
        conf[r] += a3 + b2[3];
    }
}

// ---------------- final outputs ----------------
__global__ void k_output(const float* __restrict__ coords, const float* __restrict__ vis,
                         const float* __restrict__ conf, float* __restrict__ out) {
    int r = blockIdx.x * 256 + threadIdx.x;
    if (r >= T_FR * N_Q) return;
    out[r * 2 + 0] = coords[r * 2 + 0] * 4.0f;
    out[r * 2 + 1] = coords[r * 2 + 1] * 4.0f;
    out[4096 + r] = 1.0f / (1.0f + expf(-vis[r]));
    out[6144 + r] = 1.0f / (1.0f + expf(-conf[r]));
}

extern "C" void kernel_launch(void* const* d_in, const int* in_sizes, int n_in,
                              void* d_out, int out_size, void* d_ws, size_t ws_size,
                              hipStream_t stream) {
    const float* video   = (const float*)d_in[0];
    const float* queries = (const float*)d_in[1];
    const float* fnet_w  = (const float*)d_in[2];
    const float* fnet_b  = (const float*)d_in[3];
    const float* fc1_w   = (const float*)d_in[4];
    const float* fc1_b   = (const float*)d_in[5];
    const float* fc2_w   = (const float*)d_in[6];
    const float* fc2_b   = (const float*)d_in[7];
    const float* up_w1   = (const float*)d_in[8];
    const float* up_b1   = (const float*)d_in[9];
    const float* up_w2   = (const float*)d_in[10];
    const float* up_b2   = (const float*)d_in[11];
    const float* t_emb   = (const float*)d_in[12];

    char* wsb = (char*)d_ws;
    size_t off = 0;
    #define ALLOC_US(name, elems) unsigned short* name = (unsigned short*)(wsb + off); off += ((size_t)(elems) * 2 + 15) & ~15ull;
    #define ALLOC_F(name, elems)  float* name = (float*)(wsb + off); off += ((size_t)(elems) * 4 + 15) & ~15ull;
    ALLOC_US(pyr0, (size_t)16 * 96 * 128 * 128)
    ALLOC_US(pyr1, (size_t)16 * 48 * 64 * 128)
    ALLOC_US(pyr2, (size_t)16 * 24 * 32 * 128)
    ALLOC_US(pyr3, (size_t)16 * 12 * 16 * 128)
    ALLOC_US(tfs,  (size_t)4 * N_Q * 64 * 128)
    ALLOC_US(cv,   (size_t)8192 * KCV)
    ALLOC_US(h1,   (size_t)8192 * 384)
    ALLOC_US(xb,   (size_t)2048 * KU)
    ALLOC_US(wt1,  (size_t)384 * KCV)
    ALLOC_US(wt2,  (size_t)256 * 384)
    ALLOC_US(wtu,  (size_t)384 * KU)
    ALLOC_US(wcv,  (size_t)128 * 64)
    ALLOC_F(pp,   (size_t)4 * 8192 * 384)
    ALLOC_F(te,   (size_t)T_FR * DIN)
    ALLOC_F(crd,  (size_t)2048 * 2)
    ALLOC_F(vis,  2048)
    ALLOC_F(conf, 2048)

    k_te<<<(T_FR * DIN + 255) / 256, 256, 0, stream>>>(t_emb, te);
    k_init<<<8, 256, 0, stream>>>(queries, crd, vis, conf);
    hipMemsetAsync(wt1, 0, (size_t)384 * KCV * 2, stream);
    k_prep1<<<(2401 * 384 + 255) / 256, 256, 0, stream>>>(fc1_w, wt1);
    k_prep<<<(384 * 256 + 255) / 256, 256, 0, stream>>>(fc2_w, wt2, 384, 256, 384, 384 * 256);
    k_prep<<<(DIN * 384 + 255) / 256, 256, 0, stream>>>(up_w1, wtu, DIN, 384, KU, DIN * 384);
    k_prepc<<<32, 256, 0, stream>>>(fnet_w, wcv);
    k_conv<<<dim3(96, 16), 256, 0, stream>>>(video, wcv, fnet_b, pyr0);
    k_pool<<<(16 * 48 * 64 * 16 + 255) / 256, 256, 0, stream>>>(pyr0, pyr1, 48, 64, 16 * 48 * 64 * 16);
    k_pool<<<(16 * 24 * 32 * 16 + 255) / 256, 256, 0, stream>>>(pyr1, pyr2, 24, 32, 16 * 24 * 32 * 16);
    k_pool<<<(16 * 12 * 16 * 16 + 255) / 256, 256, 0, stream>>>(pyr2, pyr3, 12, 16, 16 * 12 * 16 * 16);
    k_template<<<4 * N_Q, 256, 0, stream>>>(queries, pyr0, pyr1, pyr2, pyr3, tfs);

    for (int it = 0; it < ITERS; ++it) {
        k_corr<<<8192, 256, 0, stream>>>(pyr0, pyr1, pyr2, pyr3, tfs, crd, cv);
        k_ms128<<<768, 256, 0, stream>>>(cv, wt1, pp, KCV, 3, 64, 384, 80, 4, 8192);
        k_redasm<<<4096, 256, 0, stream>>>(pp, fc1_b, h1, crd, vis, conf, te, xb);
        k_gdb<<<512, 256, 0, stream>>>(h1, wt2, fc2_b, xb, te, 384, 4, 128, 0, 2);
        k_gdb<<<192, 256, 0, stream>>>(xb, wtu, up_b1, h1, nullptr, KU, 6, 32, 384, 1);
        k_up2<<<512, 256, 0, stream>>>(h1, up_w2, up_b2, crd, vis, conf);
    }
    k_output<<<8, 256, 0, stream>>>(crd, vis, conf, (float*)d_out);
}